// Round 8
// baseline (158.564 us; speedup 1.0000x reference)
//
#include <hip/hip_runtime.h>

#define BINS        2048
#define NIMG        64
#define IMG_ELEMS   (512*512)
#define EMAX        6.5f
#define BPI         32
#define K1_THREADS  256
#define CHUNK       (IMG_ELEMS/BPI)     // 8192 elems per K1 block
#define GRID1       (NIMG*BPI)          // 2048 blocks
#define PER         (CHUNK/(K1_THREADS*4))  // 8 float4-pairs per thread
#define K2_THREADS  512

typedef unsigned int u32;
typedef unsigned long long u64;

// Count-only LDS histogram, packed (pos<<16 | neg); chunk=8192 fits u16.
// BRANCHLESS inner loop: every element issues exactly one ds_add; lanes with
// e<=0 add 0 to a per-lane scattered dummy bin (no contamination, no exec-mask
// branches). Error sums reconstructed as count*bin_center in K2.
__global__ __launch_bounds__(K1_THREADS, 6)
void lovasz_hist(const float* __restrict__ pred, const float* __restrict__ tgt,
                 u32* __restrict__ regions, u32* __restrict__ Pblk) {
    __shared__ u32 cnt[BINS];
    __shared__ u32 pw[K1_THREADS/64];
    const int bx  = blockIdx.x;
    const int img = bx >> 5, sub = bx & 31;
    const int tid = threadIdx.x;

    {   // 8KB init: 2 ds_write_b128 per thread
        uint4 z; z.x = z.y = z.z = z.w = 0u;
        ((uint4*)cnt)[tid] = z;
        ((uint4*)cnt)[tid + K1_THREADS] = z;
    }
    __syncthreads();

    const size_t base = (size_t)img * IMG_ELEMS + (size_t)sub * CHUNK;
    const float4* p4 = (const float4*)(pred + base);
    const float4* t4 = (const float4*)(tgt + base);
    const float scale = (float)BINS / EMAX;

    u32 posc = 0;
    // rolling pipeline: issue next float4-pair before processing current
    float4 pv = p4[tid], tv = t4[tid];
    #pragma unroll
    for (int k = 0; k < PER; ++k) {
        float4 pn, tn;
        if (k < PER - 1) {
            pn = p4[tid + (k + 1) * K1_THREADS];
            tn = t4[tid + (k + 1) * K1_THREADS];
        }
        float pa[4] = {pv.x, pv.y, pv.z, pv.w};
        float ta[4] = {tv.x, tv.y, tv.z, tv.w};
        #pragma unroll
        for (int q = 0; q < 4; ++q) {
            bool pos = ta[q] > 0.5f;
            posc += pos ? 1u : 0u;                       // P counts ALL positives
            // e = 1 -/+ p ; binf = e*scale via one fma with selected sign
            float binf = fmaf(pa[q], pos ? -scale : scale, scale);
            int b = (int)fminf(binf, (float)(BINS - 1)); // clamp top
            bool valid = binf > 0.f;                     // relu gate (e>0)
            int  dummy = (tid + q * K1_THREADS) & (BINS - 1); // conflict-free scatter
            b = valid ? b : dummy;
            u32 inc = valid ? (pos ? 0x10000u : 1u) : 0u;
            atomicAdd(&cnt[b], inc);                     // unconditional ds_add
        }
        pv = pn; tv = tn;
    }
    for (int off = 32; off; off >>= 1) posc += __shfl_down(posc, off, 64);
    if ((tid & 63) == 0) pw[tid >> 6] = posc;
    __syncthreads();
    if (tid == 0) {
        u32 s = 0;
        #pragma unroll
        for (int w = 0; w < K1_THREADS/64; ++w) s += pw[w];
        Pblk[bx] = s;                                    // plain store, no memset
    }
    // flush: 2 ds_read_b128 + 2 global dwordx4 per thread
    u32* reg = regions + (size_t)bx * BINS;
    ((uint4*)reg)[tid]              = ((const uint4*)cnt)[tid];
    ((uint4*)reg)[tid + K1_THREADS] = ((const uint4*)cnt)[tid + K1_THREADS];
}

// One block per image: aggregate 32 sub-hists (independent uint4 loads),
// shfl-based suffix scan over bins (descending e), fp64 closed form.
__global__ __launch_bounds__(K2_THREADS, 2)
void lovasz_loss(const u32* __restrict__ regions, const u32* __restrict__ Pblk,
                 float* __restrict__ out) {
    __shared__ u64    wtot[8];
    __shared__ u64    wsuf[8];
    __shared__ double red[8];
    __shared__ u32    Psh;
    const int img = blockIdx.x, tid = threadIdx.x;
    const int lane = tid & 63, wid = tid >> 6;
    const int b0 = tid * 4;                              // 512*4 == 2048 bins

    u32 cp[4] = {0,0,0,0}, cn[4] = {0,0,0,0};
    const u32* base = regions + (size_t)img * BPI * BINS;
    #pragma unroll
    for (int s = 0; s < BPI; ++s) {
        uint4 v = *(const uint4*)(base + (size_t)s * BINS + b0);
        cp[0] += v.x >> 16;     cp[1] += v.y >> 16;     cp[2] += v.z >> 16;     cp[3] += v.w >> 16;
        cn[0] += v.x & 0xFFFFu; cn[1] += v.y & 0xFFFFu; cn[2] += v.z & 0xFFFFu; cn[3] += v.w & 0xFFFFu;
    }

    u32 pc = (tid < BPI) ? Pblk[img * BPI + tid] : 0u;
    if (wid == 0) {
        for (int off = 32; off; off >>= 1) pc += __shfl_down(pc, off, 64);
        if (lane == 0) Psh = pc;
    }

    u64 own = ((u64)(cp[0]+cp[1]+cp[2]+cp[3]) << 32) | (u64)(cn[0]+cn[1]+cn[2]+cn[3]);

    // intra-wave inclusive suffix scan (bins ascend with tid; "above" = higher tid)
    u64 x = own;
    #pragma unroll
    for (int off = 1; off < 64; off <<= 1) {
        u64 v = __shfl_down(x, off, 64);
        if (lane + off < 64) x += v;
    }
    if (lane == 0) wtot[wid] = x;
    __syncthreads();
    if (tid < 8) {
        u64 w = wtot[tid];
        #pragma unroll
        for (int off = 1; off < 8; off <<= 1) {
            u64 v = __shfl_down(w, off, 64);
            if (tid + off < 8) w += v;
        }
        wsuf[tid] = w;                                   // inclusive suffix over waves
    }
    __syncthreads();
    u64 above = (x - own) + ((wid < 7) ? wsuf[wid + 1] : 0ull);

    const double P = (double)Psh;
    double p_above = (double)(u32)(above >> 32);
    double n_above = (double)(u32)(above & 0xFFFFFFFFull);
    const double binw = (double)EMAX / (double)BINS;
    double acc = 0.0;
    #pragma unroll
    for (int j = 3; j >= 0; --j) {                       // own bins, descending e
        double a = (double)cp[j], c = (double)cn[j];
        double Pn = P + n_above;
        double ctr = ((double)(b0 + j) + 0.5) * binw;
        if (Pn > 0.0) {
            // positives first: a*ctr/Pn ; negatives (rank-exact telescoped):
            acc += a * ctr / Pn
                 + c * ctr * (P - p_above - a) / (Pn * (Pn + c));
        }
        p_above += a; n_above += c;
    }
    for (int off = 32; off; off >>= 1) acc += __shfl_down(acc, off, 64);
    if (lane == 0) red[wid] = acc;
    __syncthreads();
    if (tid == 0) {
        double tot = 0.0;
        #pragma unroll
        for (int w = 0; w < 8; ++w) tot += red[w];
        atomicAdd(out, (float)(tot / (double)NIMG));
    }
}

extern "C" void kernel_launch(void* const* d_in, const int* in_sizes, int n_in,
                              void* d_out, int out_size, void* d_ws, size_t ws_size,
                              hipStream_t stream) {
    const float* pred = (const float*)d_in[0];
    const float* tgt  = (const float*)d_in[1];

    u32* regions = (u32*)d_ws;                                      // 2048 x 8KB = 16 MB
    u32* Pblk    = (u32*)((char*)d_ws + (size_t)GRID1 * BINS * 4);  // 8 KB

    hipMemsetAsync(d_out, 0, sizeof(float), stream);

    lovasz_hist<<<GRID1, K1_THREADS, 0, stream>>>(pred, tgt, regions, Pblk);
    lovasz_loss<<<NIMG,  K2_THREADS, 0, stream>>>(regions, Pblk, (float*)d_out);
}